// Round 9
// baseline (35.550 us; speedup 1.0000x reference)
//
#include <hip/hip_runtime.h>

#define MARGIN 0.1f
#define B 512
#define P 4
#define N 64
#define D 1024
#define NV (P + N)   // 68 score vectors per batch row
#define FIXSCALE 1048576.0  // 2^20 fixed-point scale

// Native vector type for nontemporal builtins (HIP_vector_type is rejected).
typedef float f32x4 __attribute__((ext_vector_type(4)));

// Non-temporal 16B load: streaming data with zero reuse.
__device__ __forceinline__ f32x4 nt_load4(const float* p) {
    return __builtin_nontemporal_load((const f32x4*)p);
}

// One block per batch row b. 1024 threads = 16 waves -> 32 waves/CU.
// Single compute dispatch. Tail: deterministic i64 fixed-point atomicAdd
// (relaxed, device scope — NO release/acquire, so no L2 wb/inv; that's
// what killed the R4/R6 fusions). The block whose count-add returns B-1
// fetches the exact total and writes the mean.
__global__ __launch_bounds__(1024) void loss_kernel(
    const float* __restrict__ q,     // [B, D]
    const float* __restrict__ pos,   // [B, P, D]
    const float* __restrict__ neg,   // [B, N, D]
    unsigned long long* __restrict__ acc_sum, // [1] d_ws, memset 0 per call
    unsigned* __restrict__ acc_cnt,           // [1] d_ws, memset 0 per call
    float* __restrict__ out)         // [1]
{
    const int b    = blockIdx.x;
    const int tid  = threadIdx.x;
    const int lane = tid & 63;
    const int wave = tid >> 6;       // 0..15

    // Each lane keeps 16 query floats (4 x float4), coalesced 1KB/load.
    // All 16 waves read the same 4KB row -> keep CACHED (L1 reuse).
    const float4* q4 = (const float4*)(q + (size_t)b * D);
    float4 qv[4];
#pragma unroll
    for (int i = 0; i < 4; ++i) qv[i] = q4[i * 64 + lane];

    __shared__ float scores[NV];     // [0..3]=pos, [4..67]=neg

    // 68 vectors over 16 waves: waves 0-3 do 5, waves 4-15 do 4.
    for (int v = wave; v < NV; v += 16) {
        const float* vec = (v < P)
            ? (pos + ((size_t)b * P + v) * D)
            : (neg + ((size_t)b * N + (v - P)) * D);
        float acc = 0.0f;
#pragma unroll
        for (int i = 0; i < 4; ++i) {
            f32x4 x = nt_load4(vec + (i * 64 + lane) * 4);
            acc += qv[i].x * x.x + qv[i].y * x.y + qv[i].z * x.z + qv[i].w * x.w;
        }
#pragma unroll
        for (int off = 32; off > 0; off >>= 1)
            acc += __shfl_down(acc, off, 64);
        if (lane == 0) scores[v] = acc;
    }
    __syncthreads();

    // Pairwise: 4*64 = 256 pairs on waves 0..3 (one pair per thread).
    __shared__ float wsum[4];
    if (wave < 4) {
        float ps  = scores[wave];            // pos index
        float ns  = scores[P + lane];        // neg index
        float val = fmaxf(MARGIN - ps + ns, 0.0f);
#pragma unroll
        for (int off = 32; off > 0; off >>= 1)
            val += __shfl_down(val, off, 64);
        if (lane == 0) wsum[wave] = val;
    }
    __syncthreads();

    if (tid == 0) {
        float s = wsum[0] + wsum[1] + wsum[2] + wsum[3];
        // Exact, order-independent accumulation: i64 fixed point (2^20).
        // Double conversion so no float-mantissa loss at |s|~5e3.
        long long ll = __double2ll_rn((double)s * FIXSCALE);
        atomicAdd(acc_sum, (unsigned long long)ll);
        // Drain the sum-add to the coherent point before the count-add:
        // any block observing our count increment is then guaranteed our
        // sum contribution is already applied.
        __asm__ volatile("s_waitcnt vmcnt(0)" ::: "memory");
        unsigned cnt_old = atomicAdd(acc_cnt, 1u);
        if (cnt_old == (unsigned)(B - 1)) {
            // Last arrival: all B sum-adds are at the coherent point.
            // Atomic fetch (add 0) bypasses stale caches.
            unsigned long long tot = atomicAdd(acc_sum, 0ull);
            double tv = (double)(long long)tot * (1.0 / FIXSCALE);
            out[0] = (float)(tv / (double)(B * P * N));
        }
    }
}

extern "C" void kernel_launch(void* const* d_in, const int* in_sizes, int n_in,
                              void* d_out, int out_size, void* d_ws, size_t ws_size,
                              hipStream_t stream) {
    const float* q   = (const float*)d_in[0];   // [512,1024]
    const float* pos = (const float*)d_in[1];   // [512,4,1024]
    const float* neg = (const float*)d_in[2];   // [512,64,1024]
    float* out       = (float*)d_out;
    unsigned long long* acc_sum = (unsigned long long*)d_ws;      // offset 0
    unsigned* acc_cnt = (unsigned*)((char*)d_ws + 8);             // offset 8

    // Zero the 16-byte accumulator block every call (capture-safe node).
    hipMemsetAsync(d_ws, 0, 16, stream);
    loss_kernel<<<B, 1024, 0, stream>>>(q, pos, neg, acc_sum, acc_cnt, out);
}

// Round 10
// 26.468 us; speedup vs baseline: 1.3431x; 1.3431x over previous
//
#include <hip/hip_runtime.h>

#define MARGIN 0.1f
#define B 512
#define P 4
#define N 64
#define D 1024
#define NV (P + N)   // 68 score vectors per batch row

// Native vector type for nontemporal builtins (HIP_vector_type is rejected).
typedef float f32x4 __attribute__((ext_vector_type(4)));

// Non-temporal 16B load: streaming data with zero reuse -> don't
// allocate in caches (emits global_load_dwordx4 ... nt).
__device__ __forceinline__ f32x4 nt_load4(const float* p) {
    return __builtin_nontemporal_load((const f32x4*)p);
}

// One block per batch row b. 1024 threads = 16 waves -> 32 waves/CU at
// 2 blocks/CU. Best-measured structure (R8, 26.47 us): two dispatches;
// all fusion variants (cooperative, acq_rel ticket, relaxed atomics +
// memset node) measured SLOWER than the finalize dispatch they remove.
__global__ __launch_bounds__(1024) void scores_kernel(
    const float* __restrict__ q,     // [B, D]
    const float* __restrict__ pos,   // [B, P, D]
    const float* __restrict__ neg,   // [B, N, D]
    float* __restrict__ partial)     // [B]
{
    const int b    = blockIdx.x;
    const int tid  = threadIdx.x;
    const int lane = tid & 63;
    const int wave = tid >> 6;       // 0..15

    // Each lane keeps 16 query floats (4 x float4), coalesced 1KB/load.
    // All 16 waves read the same 4KB row -> keep CACHED (L1 reuse).
    const float4* q4 = (const float4*)(q + (size_t)b * D);
    float4 qv[4];
#pragma unroll
    for (int i = 0; i < 4; ++i) qv[i] = q4[i * 64 + lane];

    __shared__ float scores[NV];     // [0..3]=pos, [4..67]=neg

    // 68 vectors over 16 waves: waves 0-3 do 5, waves 4-15 do 4.
    for (int v = wave; v < NV; v += 16) {
        const float* vec = (v < P)
            ? (pos + ((size_t)b * P + v) * D)
            : (neg + ((size_t)b * N + (v - P)) * D);
        float acc = 0.0f;
#pragma unroll
        for (int i = 0; i < 4; ++i) {
            f32x4 x = nt_load4(vec + (i * 64 + lane) * 4);
            acc += qv[i].x * x.x + qv[i].y * x.y + qv[i].z * x.z + qv[i].w * x.w;
        }
#pragma unroll
        for (int off = 32; off > 0; off >>= 1)
            acc += __shfl_down(acc, off, 64);
        if (lane == 0) scores[v] = acc;
    }
    __syncthreads();

    // Pairwise: 4*64 = 256 pairs on waves 0..3 (one pair per thread).
    __shared__ float wsum[4];
    if (wave < 4) {
        float ps  = scores[wave];            // pos index
        float ns  = scores[P + lane];        // neg index
        float val = fmaxf(MARGIN - ps + ns, 0.0f);
#pragma unroll
        for (int off = 32; off > 0; off >>= 1)
            val += __shfl_down(val, off, 64);
        if (lane == 0) wsum[wave] = val;
    }
    __syncthreads();
    if (tid == 0)
        partial[b] = wsum[0] + wsum[1] + wsum[2] + wsum[3];
}

// Deterministic final reduction: one wave, 8 partials per lane, no syncs.
__global__ __launch_bounds__(64) void finalize_kernel(
    const float* __restrict__ partial, float* __restrict__ out)
{
    const int lane = threadIdx.x;
    float v = 0.0f;
#pragma unroll
    for (int k = 0; k < 8; ++k)
        v += partial[lane + 64 * k];
#pragma unroll
    for (int off = 32; off > 0; off >>= 1)
        v += __shfl_down(v, off, 64);
    if (lane == 0)
        out[0] = v / (float)(B * P * N);
}

extern "C" void kernel_launch(void* const* d_in, const int* in_sizes, int n_in,
                              void* d_out, int out_size, void* d_ws, size_t ws_size,
                              hipStream_t stream) {
    const float* q   = (const float*)d_in[0];   // [512,1024]
    const float* pos = (const float*)d_in[1];   // [512,4,1024]
    const float* neg = (const float*)d_in[2];   // [512,64,1024]
    float* out       = (float*)d_out;
    float* partial   = (float*)d_ws;            // 512 floats

    scores_kernel<<<B, 1024, 0, stream>>>(q, pos, neg, partial);
    finalize_kernel<<<1, 64, 0, stream>>>(partial, out);
}